// Round 2
// 158.206 us; speedup vs baseline: 1.1285x; 1.1285x over previous
//
#include <hip/hip_runtime.h>

#define NS 4096
#define NCC 1024
#define DD 64
#define HH2 32
#define NSEQ 32
#define SLEN 256
#define SLOTS 8192
#define LNEPS 1e-3f
#define MAXCH 96      // max sites per 32-slot chunk (mean 16, 20 sigma margin)

// ---------------- K_setup: blocks 0-19 = prep (256 rows each), blocks 20-21 = counting sort ----------------
__global__ void __launch_bounds__(1024) k_setup(
    const float* __restrict__ sites, const float* __restrict__ cons,
    const float* __restrict__ Ws, const float* __restrict__ bs,
    const float* __restrict__ Wc, const float* __restrict__ bc,
    const float* __restrict__ Wd, const float* __restrict__ bd,
    const float* __restrict__ g, const float* __restrict__ Wo,
    float* __restrict__ u, float* __restrict__ A, float* __restrict__ P,
    float* __restrict__ v, float* __restrict__ B, float* __restrict__ Q,
    const int* __restrict__ idxl, const int* __restrict__ idxh,
    int* __restrict__ offl, int* __restrict__ slotl, int* __restrict__ sitel,
    int* __restrict__ offh, int* __restrict__ sloth, int* __restrict__ siteh) {
  __shared__ int cnt[SLOTS];
  __shared__ int wsumI[16];
  int tid = threadIdx.x;
  if (blockIdx.x < 20) {
    // ---- prep: 4 waves/block, one row per thread ----
    if (tid >= 256) return;
    int t = blockIdx.x * 256 + tid;
    if (t >= NS + NCC) return;
    bool isSite = t < NS;
    int row = isSite ? t : t - NS;
    const float* x = isSite ? sites + row * DD : cons + row * DD;
    const float* W1 = isSite ? Ws : Wc;
    const float* b1 = isSite ? bs : bc;
    float s[HH2];
#pragma unroll
    for (int h = 0; h < HH2; h++) s[h] = b1[h];
    for (int k = 0; k < DD; k++) {
      float xv = x[k];
#pragma unroll
      for (int h = 0; h < HH2; h++) s[h] = fmaf(xv, W1[k * HH2 + h], s[h]);
    }
#pragma unroll
    for (int h = 0; h < HH2; h++) s[h] = fmaxf(s[h], 0.0f);
    float hs[HH2];
#pragma unroll
    for (int h = 0; h < HH2; h++) hs[h] = isSite ? 0.0f : bd[h];  // b_d folded into con side
    for (int k = 0; k < HH2; k++) {
      float sv = s[k];
#pragma unroll
      for (int h = 0; h < HH2; h++) hs[h] = fmaf(sv, Wd[k * HH2 + h], hs[h]);
    }
    float mu = 0.f;
#pragma unroll
    for (int h = 0; h < HH2; h++) mu += hs[h];
    mu *= (1.0f / HH2);
    float p = 0.f, a = 0.f;
    float* dst = isSite ? (u + row * HH2) : (v + row * HH2);
#pragma unroll
    for (int h = 0; h < HH2; h++) {
      float uu = hs[h] - mu;
      dst[h] = uu;
      p += uu * uu;
      a = fmaf(uu * g[h], Wo[h], a);
    }
    p *= (1.0f / HH2);
    if (isSite) { A[row] = a; P[row] = p; } else { B[row] = a; Q[row] = p; }
    return;
  }
  // ---- sort (blocks 20,21) ----
  int lane = tid & 63, wv = tid >> 6;
  int pass = blockIdx.x - 20;
  const int* idx = pass ? idxh : idxl;
  int* off = pass ? offh : offl;
  int* slotA = pass ? sloth : slotl;
  int* siteA = pass ? siteh : sitel;
  for (int i2 = tid; i2 < SLOTS; i2 += 1024) cnt[i2] = 0;
  __syncthreads();
  for (int i2 = tid; i2 < NS; i2 += 1024) atomicAdd(&cnt[idx[i2]], 1);
  __syncthreads();
  int base = tid * 8;
  int loc[8]; int sum = 0;
#pragma unroll
  for (int q2 = 0; q2 < 8; q2++) { loc[q2] = sum; sum += cnt[base + q2]; }
  int incl = sum;
#pragma unroll
  for (int o = 1; o < 64; o <<= 1) { int t2 = __shfl_up(incl, o); if (lane >= o) incl += t2; }
  if (lane == 63) wsumI[wv] = incl;
  __syncthreads();
  int wprev = 0;
#pragma unroll
  for (int w = 0; w < 16; w++) { int t3 = wsumI[w]; if (w < wv) wprev += t3; }
  int excl = wprev + (incl - sum);
  __syncthreads();
#pragma unroll
  for (int q2 = 0; q2 < 8; q2++) { int o2 = excl + loc[q2]; off[base + q2] = o2; cnt[base + q2] = o2; }
  if (tid == 0) off[SLOTS] = NS;
  __syncthreads();
  for (int i2 = tid; i2 < NS; i2 += 1024) {
    int sl = idx[i2];
    int pos = atomicAdd(&cnt[sl], 1);
    slotA[pos] = sl; siteA[pos] = i2;
  }
}

// ---------------- K_main: logits -> softmax -> cumsums; 16 rows/block, no max phase, 1 barrier ----------------
// Logits are structurally bounded (|logit| ~< 15): exp() cannot overflow f32;
// normalization makes the result identical to max-shifted softmax.
__global__ void __launch_bounds__(1024) k_main(const float* __restrict__ u,
    const float* __restrict__ A, const float* __restrict__ P,
    const float* __restrict__ v, const float* __restrict__ B, const float* __restrict__ Q,
    const float* __restrict__ lnb, const float* __restrict__ Wo, const float* __restrict__ bo,
    float* __restrict__ M, float* __restrict__ CLp, float* __restrict__ CHp) {
  int j = threadIdx.x;
  int lane = j & 63, wv = j >> 6;
  __shared__ float redB[16 * 16];  // [row][wave] wave sums
  float4 vv[8];
  const float4* vp = (const float4*)(v + j * HH2);
#pragma unroll
  for (int q = 0; q < 8; q++) vv[q] = vp[q];
  float Bj = B[j], Qj = Q[j];
  float C = bo[0];
#pragma unroll
  for (int k = 0; k < HH2; k++) C = fmaf(lnb[k], Wo[k], C);
  int row0 = blockIdx.x * 16;

  float e[16], incl[16];
#pragma unroll
  for (int rr = 0; rr < 16; rr++) {
    int i = row0 + rr;
    const float4* up = (const float4*)(u + i * HH2);
    float dot = 0.f;
#pragma unroll
    for (int q = 0; q < 8; q++) {
      float4 u4 = up[q];
      dot = fmaf(u4.x, vv[q].x, dot);
      dot = fmaf(u4.y, vv[q].y, dot);
      dot = fmaf(u4.z, vv[q].z, dot);
      dot = fmaf(u4.w, vv[q].w, dot);
    }
    float var = P[i] + Qj + dot * 0.0625f;   // P + Q + 2*dot/32
    float lg = rsqrtf(var + LNEPS) * (A[i] + Bj) + C;
    float ee = __expf(lg);
    float ic = ee;
#pragma unroll
    for (int o = 1; o < 64; o <<= 1) { float tt = __shfl_up(ic, o); if (lane >= o) ic += tt; }
    if (lane == 63) redB[rr * 16 + wv] = ic;
    e[rr] = ee; incl[rr] = ic;
  }
  __syncthreads();
#pragma unroll
  for (int rr = 0; rr < 16; rr++) {
    const float4* rb = (const float4*)(redB + rr * 16);
    float4 b0 = rb[0], b1 = rb[1], b2 = rb[2], b3 = rb[3];
    float w_[16] = {b0.x, b0.y, b0.z, b0.w, b1.x, b1.y, b1.z, b1.w,
                    b2.x, b2.y, b2.z, b2.w, b3.x, b3.y, b3.z, b3.w};
    float prev = 0.f, tot = 0.f;
#pragma unroll
    for (int w = 0; w < 16; w++) { tot += w_[w]; if (w < wv) prev += w_[w]; }
    float chE = prev + incl[rr];
    float rd = 1.0f / tot;
    int o_ = (row0 + rr) * NCC + j;
    M[o_] = e[rr] * rd;                    // softmax (to d_out)
    CHp[o_] = chE * rd;                    // forward cumsum
    CLp[o_] = (tot - chE + e[rr]) * rd;    // reverse cumsum
  }
}

// ---------------- K_band: chunked exclusive-cumprod scan, both bands in one launch ----------------
// The per-(seq,col) cumprod over 256 slots is associative: split into 8 chunks of 32 slots
// (slot Z-sums never span chunks). Each block handles (coltile, band, chunk, seq): ~16 sites,
// writes the chunk-LOCAL exclusive product in place over CLp/CHp (each (site,col) is owned by
// exactly one block) and the chunk total product into TT[band][seq][chunk][col].
// Grid 2048 blocks x 4 waves (~24+ waves/CU) vs the old 256 blocks x 1 wave.
__global__ void __launch_bounds__(256) k_band(
    float* __restrict__ CLp, float* __restrict__ CHp,
    const int* __restrict__ offl, const int* __restrict__ slotl, const int* __restrict__ sitel,
    const int* __restrict__ offh, const int* __restrict__ sloth, const int* __restrict__ siteh,
    float* __restrict__ TT) {
  int band = blockIdx.y >> 3;         // 0 = lower, 1 = higher
  int chunk = blockIdx.y & 7;
  int seq = blockIdx.z;
  int j = blockIdx.x * 256 + threadIdx.x;
  const int* off = band ? offh : offl;
  const int* slA = band ? sloth : slotl;
  const int* siA = band ? siteh : sitel;
  float* C = band ? CHp : CLp;
  int slot0 = seq * SLEN + chunk * 32;
  int s0 = off[slot0];
  int n = off[slot0 + 32] - s0;
  size_t trow = ((size_t)band * 256 + seq * 8 + chunk) * NCC + j;
  if (n <= 0) { TT[trow] = 1.0f; return; }   // empty chunk: product of 32 unit factors
  if (n > MAXCH) n = MAXCH;                  // statistically impossible (20 sigma); avoid OOB
  __shared__ int ss[MAXCH];
  __shared__ int sl[MAXCH];
  for (int i = threadIdx.x; i < n; i += 256) { ss[i] = siA[s0 + i]; sl[i] = slA[s0 + i]; }
  __syncthreads();

  const int T = 32;  // covers n<=32 (P(n>32) ~ 3e-5 per chunk); all loads issued before any store
  float buf[T];
#pragma unroll
  for (int k = 0; k < T; k++) {
    int kk = k < n ? k : n - 1;
    buf[k] = C[(size_t)ss[kk] * NCC + j];
  }
  float r = 1.f, z = 0.f;
  int prev = -1;
#pragma unroll
  for (int k = 0; k < T; k++) {
    if (k < n) {
      float cv = buf[k];
      int slot = sl[k];
      if (slot != prev) {                    // uniform branch (sl in LDS, same for all lanes)
        if (prev >= 0) { r *= fmaxf(1.f - z, 0.f); z = 0.f; }
        prev = slot;
      }
      C[(size_t)ss[k] * NCC + j] = r;        // chunk-local exclusive cumprod
      z += cv;
    }
  }
  for (int k = T; k < n; k++) {              // rare tail (n > 32)
    float cv = C[(size_t)ss[k] * NCC + j];
    int slot = sl[k];
    if (slot != prev) {
      if (prev >= 0) { r *= fmaxf(1.f - z, 0.f); z = 0.f; }
      prev = slot;
    }
    C[(size_t)ss[k] * NCC + j] = r;
    z += cv;
  }
  r *= fmaxf(1.f - z, 0.f);                  // close the last occupied slot
  TT[trow] = r;                              // chunk total (empty trailing slots contribute 1)
}

// ---------------- K_prefix: exclusive product over the 8 chunk totals per (band, seq, col) ----------------
__global__ void __launch_bounds__(1024) k_prefix(float* __restrict__ TT) {
  int b = blockIdx.x;                        // band*32 + seq, 0..63
  int j = threadIdx.x;
  float* base = TT + (size_t)b * 8 * NCC + j;
  float t[8];
#pragma unroll
  for (int c = 0; c < 8; c++) t[c] = base[(size_t)c * NCC];
  float p = 1.f;
#pragma unroll
  for (int c = 0; c < 8; c++) { base[(size_t)c * NCC] = p; p *= t[c]; }
}

// ---------------- K_final: out = M * ELrel * PL * EHrel * PH — pure streaming elementwise ----------------
// PL/PH rows are indexed by idx>>5 (= seq*8+chunk); the 2 MiB TT table is L2-resident.
__global__ void __launch_bounds__(256) k_final(
    float* __restrict__ out, const float* __restrict__ ELr, const float* __restrict__ EHr,
    const float* __restrict__ TT, const int* __restrict__ idxl, const int* __restrict__ idxh) {
  int j = threadIdx.x * 4;
  int s0 = blockIdx.x * 8;
  const float* TTH = TT + (size_t)256 * NCC;
#pragma unroll 4
  for (int k = 0; k < 8; k++) {
    int s = s0 + k;
    size_t bofs = (size_t)s * NCC + j;
    float4 m  = *(const float4*)(out + bofs);
    float4 el = *(const float4*)(ELr + bofs);
    float4 eh = *(const float4*)(EHr + bofs);
    float4 pl = *(const float4*)(TT  + (size_t)(idxl[s] >> 5) * NCC + j);
    float4 ph = *(const float4*)(TTH + (size_t)(idxh[s] >> 5) * NCC + j);
    float4 o;
    o.x = m.x * el.x * pl.x * eh.x * ph.x;
    o.y = m.y * el.y * pl.y * eh.y * ph.y;
    o.z = m.z * el.z * pl.z * eh.z * ph.z;
    o.w = m.w * el.w * pl.w * eh.w * ph.w;
    *(float4*)(out + bofs) = o;
  }
}

extern "C" void kernel_launch(void* const* d_in, const int* in_sizes, int n_in,
                              void* d_out, int out_size, void* d_ws, size_t ws_size,
                              hipStream_t stream) {
  const float* sites = (const float*)d_in[0];
  const float* cons  = (const float*)d_in[1];
  const int* idxl = (const int*)d_in[2];
  const int* idxh = (const int*)d_in[3];
  const float* Ws = (const float*)d_in[4];
  const float* bs = (const float*)d_in[5];
  const float* Wc = (const float*)d_in[6];
  const float* bc = (const float*)d_in[7];
  const float* Wd = (const float*)d_in[8];
  const float* bd = (const float*)d_in[9];
  const float* lng = (const float*)d_in[10];
  const float* lnb = (const float*)d_in[11];
  const float* Wo = (const float*)d_in[12];
  const float* bo = (const float*)d_in[13];

  char* wsb = (char*)d_ws;
  size_t o = 0;
  auto alloc = [&](size_t bytes) { char* p = wsb + o; o += (bytes + 15) & ~(size_t)15; return p; };
  float* u   = (float*)alloc((size_t)NS * HH2 * 4);
  float* A   = (float*)alloc((size_t)NS * 4);
  float* P   = (float*)alloc((size_t)NS * 4);
  float* v   = (float*)alloc((size_t)NCC * HH2 * 4);
  float* B   = (float*)alloc((size_t)NCC * 4);
  float* Q   = (float*)alloc((size_t)NCC * 4);
  float* CLp = (float*)alloc((size_t)NS * NCC * 4);
  float* CHp = (float*)alloc((size_t)NS * NCC * 4);
  float* TT  = (float*)alloc((size_t)2 * 256 * NCC * 4);   // [band][seq*8+chunk][col]
  int* offl  = (int*)alloc((SLOTS + 1) * 4);
  int* slotl = (int*)alloc(NS * 4);
  int* sitel = (int*)alloc(NS * 4);
  int* offh  = (int*)alloc((SLOTS + 1) * 4);
  int* sloth = (int*)alloc(NS * 4);
  int* siteh = (int*)alloc(NS * 4);

  k_setup<<<22, 1024, 0, stream>>>(sites, cons, Ws, bs, Wc, bc, Wd, bd, lng, Wo,
                                   u, A, P, v, B, Q,
                                   idxl, idxh, offl, slotl, sitel, offh, sloth, siteh);
  k_main<<<NS / 16, 1024, 0, stream>>>(u, A, P, v, B, Q, lnb, Wo, bo,
                                       (float*)d_out, CLp, CHp);
  k_band<<<dim3(4, 16, 32), 256, 0, stream>>>(CLp, CHp,
                                              offl, slotl, sitel, offh, sloth, siteh, TT);
  k_prefix<<<64, 1024, 0, stream>>>(TT);
  k_final<<<NS / 8, 256, 0, stream>>>((float*)d_out, CLp, CHp, TT, idxl, idxh);
}